// Round 5
// baseline (1314.670 us; speedup 1.0000x reference)
//
#include <hip/hip_runtime.h>
#include <hip/hip_bf16.h>
#include <stdint.h>

#define S 4096
#define D 512
#define H 8
#define HD 64
#define SW 128  // uint32 words per bit-packed mask row (S/32)

typedef __attribute__((ext_vector_type(8))) short bf16x8;
typedef __attribute__((ext_vector_type(4))) float f32x4;

__device__ inline f32x4 mfma16(bf16x8 a, bf16x8 b, f32x4 c) {
  return __builtin_amdgcn_mfma_f32_16x16x32_bf16(a, b, c, 0, 0, 0);
}

__device__ inline unsigned short f2bf(float f) {
  union { __hip_bfloat16 h; unsigned short u; } cv;
  cv.h = __float2bfloat16(f);
  return cv.u;
}
__device__ inline float bf2f(unsigned short u) {
  union { unsigned short u; __hip_bfloat16 h; } cv;
  cv.u = u;
  return __bfloat162float(cv.h);
}

// ---------------- K0: mask element-width autodetect ----------------
// int32 0/1 data: every byte at index %4 != 0 is zero. Random bools: ~half
// nonzero (false-positive probability over 192 bytes: 2^-192).
__global__ __launch_bounds__(64) void detect_kernel(
    const unsigned char* __restrict__ a, int* __restrict__ flag) {
  int t = threadIdx.x;
  int v = a[t * 4 + 1] | a[t * 4 + 2] | a[t * 4 + 3];
#pragma unroll
  for (int o = 1; o < 64; o <<= 1) v |= __shfl_xor(v, o);
  if (t == 0) *flag = (v == 0) ? 4 : 1;
}

// ---------------- K0b: bit-pack both masks (robust to bool/int32) ----------
// abits[row][w] bit b = amask[row][w*32+b] != 0.
__global__ __launch_bounds__(256) void compress_kernel(
    const unsigned char* __restrict__ am, const unsigned char* __restrict__ lm,
    const int* __restrict__ mflag, unsigned int* __restrict__ abits,
    unsigned int* __restrict__ lbits) {
  const int row = blockIdx.x;
  const int w = threadIdx.x >> 6, lane = threadIdx.x & 63;
  const size_t ms = (size_t)(*mflag);
#pragma unroll
  for (int it = 0; it < 16; it++) {
    int c0 = w * 1024 + it * 64;
    size_t idx = ((size_t)row * S + c0 + lane) * ms;
    unsigned long long ba = __ballot(am[idx] != 0);
    unsigned long long bl = __ballot(lm[idx] != 0);
    if (lane == 0) {
      int wi = row * SW + (c0 >> 5);
      abits[wi] = (unsigned int)ba;
      abits[wi + 1] = (unsigned int)(ba >> 32);
      lbits[wi] = (unsigned int)bl;
      lbits[wi + 1] = (unsigned int)(bl >> 32);
    }
  }
}

// ---------------- K1: LayerNorm + bf16 hi/lo split ----------------
__global__ __launch_bounds__(256) void ln_kernel(
    const float* __restrict__ x, const float* __restrict__ g,
    const float* __restrict__ b, unsigned short* __restrict__ xnh,
    unsigned short* __restrict__ xnl) {
  int row = blockIdx.x;
  int t = threadIdx.x;
  float2 v = reinterpret_cast<const float2*>(x + (size_t)row * D)[t];
  float s = v.x + v.y;
  float s2 = v.x * v.x + v.y * v.y;
#pragma unroll
  for (int o = 1; o < 64; o <<= 1) {
    s += __shfl_xor(s, o);
    s2 += __shfl_xor(s2, o);
  }
  __shared__ float red[8];
  int wid = t >> 6;
  if ((t & 63) == 0) { red[wid] = s; red[4 + wid] = s2; }
  __syncthreads();
  s = red[0] + red[1] + red[2] + red[3];
  s2 = red[4] + red[5] + red[6] + red[7];
  float mu = s * (1.f / D);
  float var = s2 * (1.f / D) - mu * mu;
  float rsig = rsqrtf(var + 1e-5f);
  int i0 = 2 * t, i1 = 2 * t + 1;
  float xn0 = (v.x - mu) * rsig * g[i0] + b[i0];
  float xn1 = (v.y - mu) * rsig * g[i1] + b[i1];
  unsigned short h0 = f2bf(xn0), h1 = f2bf(xn1);
  size_t base = (size_t)row * D;
  xnh[base + i0] = h0;
  xnh[base + i1] = h1;
  xnl[base + i0] = f2bf(xn0 - bf2f(h0));
  xnl[base + i1] = f2bf(xn1 - bf2f(h1));
}

// ------------- K2: weight convert + LDS-tiled transpose -------------
// WT[col][k] = W[k][col] as bf16 (hi, and lo for Wq/Wk). Coalesced both ways.
__global__ __launch_bounds__(256) void wsplit_kernel(
    const float* __restrict__ Wq, const float* __restrict__ Wk,
    const float* __restrict__ Wv, const float* __restrict__ Wo,
    unsigned short* __restrict__ qh, unsigned short* __restrict__ ql,
    unsigned short* __restrict__ kh, unsigned short* __restrict__ kl,
    unsigned short* __restrict__ vh, unsigned short* __restrict__ oh) {
  __shared__ float tile[64][65];
  int m = blockIdx.z;
  const float* W = (m == 0) ? Wq : (m == 1) ? Wk : (m == 2) ? Wv : Wo;
  int bx = blockIdx.x * 64;  // col (j) base
  int by = blockIdx.y * 64;  // row (k) base
  int tx = threadIdx.x & 63, ty = threadIdx.x >> 6;
#pragma unroll
  for (int i = 0; i < 16; i++) {
    int r = ty + i * 4;
    tile[r][tx] = W[(size_t)(by + r) * D + bx + tx];
  }
  __syncthreads();
#pragma unroll
  for (int i = 0; i < 16; i++) {
    int r = ty + i * 4;
    float w = tile[tx][r];  // = W[by+tx][bx+r]
    unsigned short hi = f2bf(w);
    size_t to = (size_t)(bx + r) * D + by + tx;  // WT[j][k], coalesced in tx
    if (m == 0) { qh[to] = hi; ql[to] = f2bf(w - bf2f(hi)); }
    else if (m == 1) { kh[to] = hi; kl[to] = f2bf(w - bf2f(hi)); }
    else if (m == 2) { vh[to] = hi; }
    else { oh[to] = hi; }
  }
}

// ---------------- K3: QKV projections (MFMA) ----------------
// z=0: Q (hi/lo split, 3 products), z=1: K (split), z=2: V (plain, -> VT)
__global__ __launch_bounds__(256) void qkv_kernel(
    const unsigned short* __restrict__ xnh, const unsigned short* __restrict__ xnl,
    const unsigned short* __restrict__ wqh, const unsigned short* __restrict__ wql,
    const unsigned short* __restrict__ wkh, const unsigned short* __restrict__ wkl,
    const unsigned short* __restrict__ wvh,
    const float* __restrict__ bq, const float* __restrict__ bk,
    const float* __restrict__ bv,
    unsigned short* __restrict__ Qb, unsigned short* __restrict__ Kb,
    unsigned short* __restrict__ VT) {
  int z = blockIdx.z;
  int wave = threadIdx.x >> 6, lane = threadIdx.x & 63;
  int lg = lane >> 4, lr = lane & 15;
  int rtile = blockIdx.x * 64 + wave * 16;
  int ctile = blockIdx.y * 64;
  const unsigned short* wh = (z == 0) ? wqh : (z == 1) ? wkh : wvh;
  const unsigned short* wl = (z == 0) ? wql : wkl;
  const float* bias = (z == 0) ? bq : (z == 1) ? bk : bv;
  f32x4 zero = {0.f, 0.f, 0.f, 0.f};
  f32x4 acc[4] = {zero, zero, zero, zero};
  int ar = rtile + lr;
  const unsigned short* ap = xnh + (size_t)ar * D + lg * 8;
  const unsigned short* apl = xnl + (size_t)ar * D + lg * 8;
  for (int kk = 0; kk < D; kk += 32) {
    bf16x8 ah = *(const bf16x8*)(ap + kk);
    bf16x8 al = {};
    if (z < 2) al = *(const bf16x8*)(apl + kk);
#pragma unroll
    for (int nt = 0; nt < 4; nt++) {
      size_t bo_ = (size_t)(ctile + nt * 16 + lr) * D + kk + lg * 8;
      bf16x8 bh = *(const bf16x8*)(wh + bo_);
      acc[nt] = mfma16(ah, bh, acc[nt]);
      if (z < 2) {
        bf16x8 bl = *(const bf16x8*)(wl + bo_);
        acc[nt] = mfma16(ah, bl, acc[nt]);
        acc[nt] = mfma16(al, bh, acc[nt]);
      }
    }
  }
#pragma unroll
  for (int nt = 0; nt < 4; nt++) {
    int col = ctile + nt * 16 + lr;
    float bb = bias[col];
#pragma unroll
    for (int r = 0; r < 4; r++) {
      int row = rtile + lg * 4 + r;
      float val = acc[nt][r] + bb;
      if (z == 0) Qb[(size_t)row * D + col] = f2bf(val);
      else if (z == 1) Kb[(size_t)row * D + col] = f2bf(val);
      else VT[(size_t)col * S + row] = f2bf(val);
    }
  }
}

// ---------------- K4: fused attention (2-pass, fixed-shift softmax) --------
// 1D grid 256, XCD-aware decode: xcd = bid&7 owns head-group (xcd>>2) and a
// contiguous 1024-query span -> per-XCD K/V working set = 4 heads = 4 MB (L2-
// sized), reused by its 32 q-blocks. Block = 32 queries x 4 heads, 8 waves.
// Softmax: p = exp(s-50)/sum(exp(s-50)) -- shift-invariant, no max pass.
// Computed as exp2(c*A2 - B2*dm + C2): identical fma chain in both passes ->
// exact normalization. Masked: dm=1e30 -> t ~ -7e29 -> exp2 -> 0 (finite).
__global__ __launch_bounds__(512, 4) void attn_kernel(
    const unsigned short* __restrict__ Qb, const unsigned short* __restrict__ Kb,
    const unsigned short* __restrict__ VT,
    const unsigned int* __restrict__ abits,
    const unsigned int* __restrict__ lbits,
    const float* __restrict__ coords,
    float* __restrict__ attn, unsigned short* __restrict__ OH) {
  __shared__ float dm[32][132];
  __shared__ __align__(16) unsigned short pB[8][16][136];
  const int tid = threadIdx.x;
  const int wave = tid >> 6, lane = tid & 63;
  const int bid = blockIdx.x;
  const int xcd = bid & 7, slot = bid >> 3;
  const int qblock = ((xcd & 3) * 32 + slot) * 32;  // 32-query span base
  const int h = (xcd >> 2) * 4 + (wave & 3);
  const int qoff = (wave >> 2) * 16;  // this wave's row offset inside dm
  const int lg = lane >> 4, lr = lane & 15;
  const int qbase = qblock + qoff;
  const float L2E = 1.4426950408889634f;
  const float A2 = 0.125f * L2E;               // score scale * log2(e)
  const float B2 = exp2f(-(float)(h + 1)) * L2E;  // slope * log2(e)
  const float C2 = -50.f * L2E;                // fixed shift
  bf16x8 qf0, qf1;
  {
    const unsigned short* qp = Qb + (size_t)(qbase + lr) * D + h * HD + lg * 8;
    qf0 = *(const bf16x8*)qp;
    qf1 = *(const bf16x8*)(qp + 32);
  }
  float lsum[4] = {0.f, 0.f, 0.f, 0.f};

  // ---- pass 1: row sums of exp(s - 50) ----
  for (int kt = 0; kt < S; kt += 128) {
    __syncthreads();
#pragma unroll
    for (int p = 0; p < 8; p++) {
      int idx = tid + p * 512;
      int qi = idx >> 7, kj = idx & 127;
      int q = qblock + qi, k = kt + kj;
      int wi = q * SW + ((kt + kj) >> 5);
      float dv = 0.f;
      if ((abits[wi] >> (kj & 31)) & 1u) dv = 1e30f;
      else if ((lbits[wi] >> (kj & 31)) & 1u) {
        float dx = coords[2 * q] - coords[2 * k];
        float dy = coords[2 * q + 1] - coords[2 * k + 1];
        dv = sqrtf(dx * dx + dy * dy + 1e-12f);
      }
      dm[qi][kj] = dv;
    }
    __syncthreads();
#pragma unroll
    for (int kk = 0; kk < 8; kk++) {
      const unsigned short* kp = Kb + (size_t)(kt + kk * 16 + lr) * D + h * HD + lg * 8;
      bf16x8 kf0 = *(const bf16x8*)kp;
      bf16x8 kf1 = *(const bf16x8*)(kp + 32);
      f32x4 c = {0.f, 0.f, 0.f, 0.f};
      c = mfma16(qf0, kf0, c);
      c = mfma16(qf1, kf1, c);
#pragma unroll
      for (int r = 0; r < 4; r++) {
        float t = fmaf(c[r], A2, fmaf(-B2, dm[qoff + lg * 4 + r][kk * 16 + lr], C2));
        lsum[r] += exp2f(t);
      }
    }
  }
  // reduce row sums across the 16 lanes of each lg group
#pragma unroll
  for (int r = 0; r < 4; r++) {
#pragma unroll
    for (int o = 1; o < 16; o <<= 1) lsum[r] += __shfl_xor(lsum[r], o);
  }
  float rl[4];
#pragma unroll
  for (int r = 0; r < 4; r++) rl[r] = 1.f / lsum[r];
  f32x4 zero = {0.f, 0.f, 0.f, 0.f};
  f32x4 oacc[4] = {zero, zero, zero, zero};

  // ---- pass 2: recompute scores (identical fma chain), write attn, PV ----
  for (int kt = 0; kt < S; kt += 128) {
    __syncthreads();
#pragma unroll
    for (int p = 0; p < 8; p++) {
      int idx = tid + p * 512;
      int qi = idx >> 7, kj = idx & 127;
      int q = qblock + qi, k = kt + kj;
      int wi = q * SW + ((kt + kj) >> 5);
      float dv = 0.f;
      if ((abits[wi] >> (kj & 31)) & 1u) dv = 1e30f;
      else if ((lbits[wi] >> (kj & 31)) & 1u) {
        float dx = coords[2 * q] - coords[2 * k];
        float dy = coords[2 * q + 1] - coords[2 * k + 1];
        dv = sqrtf(dx * dx + dy * dy + 1e-12f);
      }
      dm[qi][kj] = dv;
    }
    __syncthreads();
#pragma unroll
    for (int kk = 0; kk < 8; kk++) {
      const unsigned short* kp = Kb + (size_t)(kt + kk * 16 + lr) * D + h * HD + lg * 8;
      bf16x8 kf0 = *(const bf16x8*)kp;
      bf16x8 kf1 = *(const bf16x8*)(kp + 32);
      f32x4 c = {0.f, 0.f, 0.f, 0.f};
      c = mfma16(qf0, kf0, c);
      c = mfma16(qf1, kf1, c);
#pragma unroll
      for (int r = 0; r < 4; r++) {
        float t = fmaf(c[r], A2, fmaf(-B2, dm[qoff + lg * 4 + r][kk * 16 + lr], C2));
        float pv = exp2f(t) * rl[r];
        __builtin_nontemporal_store(
            pv, &attn[((size_t)h * S + qbase + lg * 4 + r) * S + kt + kk * 16 + lr]);
        pB[wave][lg * 4 + r][kk * 16 + lr] = f2bf(pv);
      }
    }
    // no block barrier needed: pB is produced and consumed by the same wave
    // (intra-wave LDS ordering via compiler lgkmcnt); dm is protected by the
    // top-of-loop barrier.
#pragma unroll
    for (int ks = 0; ks < 4; ks++) {
      bf16x8 pa = *(const bf16x8*)&pB[wave][lr][ks * 32 + lg * 8];
#pragma unroll
      for (int nt = 0; nt < 4; nt++) {
        const unsigned short* vp =
            VT + (size_t)(h * HD + nt * 16 + lr) * S + kt + ks * 32 + lg * 8;
        bf16x8 vb = *(const bf16x8*)vp;
        oacc[nt] = mfma16(pa, vb, oacc[nt]);
      }
    }
  }
#pragma unroll
  for (int nt = 0; nt < 4; nt++) {
#pragma unroll
    for (int r = 0; r < 4; r++) {
      OH[(size_t)(qbase + lg * 4 + r) * D + h * HD + nt * 16 + lr] =
          f2bf(oacc[nt][r]);
    }
  }
}

// ---------------- K5: output projection ----------------
__global__ __launch_bounds__(256) void oproj_kernel(
    const unsigned short* __restrict__ OH, const unsigned short* __restrict__ woh,
    const float* __restrict__ bo, float* __restrict__ out) {
  int wave = threadIdx.x >> 6, lane = threadIdx.x & 63;
  int lg = lane >> 4, lr = lane & 15;
  int rtile = blockIdx.x * 64 + wave * 16;
  int ctile = blockIdx.y * 64;
  f32x4 zero = {0.f, 0.f, 0.f, 0.f};
  f32x4 acc[4] = {zero, zero, zero, zero};
  const unsigned short* ap = OH + (size_t)(rtile + lr) * D + lg * 8;
  for (int kk = 0; kk < D; kk += 32) {
    bf16x8 a = *(const bf16x8*)(ap + kk);
#pragma unroll
    for (int nt = 0; nt < 4; nt++) {
      bf16x8 b = *(const bf16x8*)(woh + (size_t)(ctile + nt * 16 + lr) * D + kk + lg * 8);
      acc[nt] = mfma16(a, b, acc[nt]);
    }
  }
#pragma unroll
  for (int nt = 0; nt < 4; nt++) {
    int col = ctile + nt * 16 + lr;
    float bb = bo[col];
#pragma unroll
    for (int r = 0; r < 4; r++) {
      out[(size_t)(rtile + lg * 4 + r) * D + col] = acc[nt][r] + bb;
    }
  }
}

extern "C" void kernel_launch(void* const* d_in, const int* in_sizes, int n_in,
                              void* d_out, int out_size, void* d_ws,
                              size_t ws_size, hipStream_t stream) {
  const float* x = (const float*)d_in[0];
  const float* coords = (const float*)d_in[1];
  const unsigned char* amask = (const unsigned char*)d_in[2];
  const unsigned char* almask = (const unsigned char*)d_in[3];
  const float* ln_g = (const float*)d_in[4];
  const float* ln_b = (const float*)d_in[5];
  const float* Wq = (const float*)d_in[6];
  const float* bq = (const float*)d_in[7];
  const float* Wk = (const float*)d_in[8];
  const float* bk = (const float*)d_in[9];
  const float* Wv = (const float*)d_in[10];
  const float* bv = (const float*)d_in[11];
  const float* Wo = (const float*)d_in[12];
  const float* bo = (const float*)d_in[13];

  float* out = (float*)d_out;
  float* attn = out + (size_t)S * D;  // outputs concatenated: out, then attn

  char* w = (char*)d_ws;
  int* mflag = (int*)w; w += 256;
  const size_t sz_xn = (size_t)S * D * 2;  // 4 MB
  const size_t sz_w = (size_t)D * D * 2;   // 0.5 MB
  const size_t sz_bits = (size_t)S * SW * 4;  // 2 MB
  unsigned short* xnh = (unsigned short*)w; w += sz_xn;
  unsigned short* xnl = (unsigned short*)w; w += sz_xn;
  unsigned short* wqh = (unsigned short*)w; w += sz_w;
  unsigned short* wql = (unsigned short*)w; w += sz_w;
  unsigned short* wkh = (unsigned short*)w; w += sz_w;
  unsigned short* wkl = (unsigned short*)w; w += sz_w;
  unsigned short* wvh = (unsigned short*)w; w += sz_w;
  unsigned short* woh = (unsigned short*)w; w += sz_w;
  unsigned short* Qb = (unsigned short*)w; w += sz_xn;
  unsigned short* Kb = (unsigned short*)w; w += sz_xn;
  unsigned short* VT = (unsigned short*)w; w += sz_xn;
  unsigned short* OH = (unsigned short*)w; w += sz_xn;
  unsigned int* abits = (unsigned int*)w; w += sz_bits;
  unsigned int* lbits = (unsigned int*)w; w += sz_bits;

  detect_kernel<<<1, 64, 0, stream>>>(amask, mflag);
  compress_kernel<<<S, 256, 0, stream>>>(amask, almask, mflag, abits, lbits);
  ln_kernel<<<S, 256, 0, stream>>>(x, ln_g, ln_b, xnh, xnl);
  wsplit_kernel<<<dim3(8, 8, 4), 256, 0, stream>>>(Wq, Wk, Wv, Wo, wqh, wql,
                                                   wkh, wkl, wvh, woh);
  qkv_kernel<<<dim3(64, 8, 3), 256, 0, stream>>>(xnh, xnl, wqh, wql, wkh, wkl,
                                                 wvh, bq, bk, bv, Qb, Kb, VT);
  attn_kernel<<<256, 512, 0, stream>>>(Qb, Kb, VT, abits, lbits,
                                       coords, attn, OH);
  oproj_kernel<<<dim3(64, 8), 256, 0, stream>>>(OH, woh, bo, out);
}

// Round 7
// 1239.908 us; speedup vs baseline: 1.0603x; 1.0603x over previous
//
#include <hip/hip_runtime.h>
#include <hip/hip_bf16.h>
#include <stdint.h>

#define S 4096
#define D 512
#define H 8
#define HD 64
#define SW 128  // uint32 words per bit-packed mask row (S/32)
#define KC_SUM 4    // key chunks in sum pass (1024 keys each)
#define KC_WR 2     // key chunks in write pass (2048 keys each)

typedef __attribute__((ext_vector_type(8))) short bf16x8;
typedef __attribute__((ext_vector_type(4))) float f32x4;

__device__ inline f32x4 mfma16(bf16x8 a, bf16x8 b, f32x4 c) {
  return __builtin_amdgcn_mfma_f32_16x16x32_bf16(a, b, c, 0, 0, 0);
}

__device__ inline unsigned short f2bf(float f) {
  union { __hip_bfloat16 h; unsigned short u; } cv;
  cv.h = __float2bfloat16(f);
  return cv.u;
}
__device__ inline float bf2f(unsigned short u) {
  union { unsigned short u; __hip_bfloat16 h; } cv;
  cv.u = u;
  return __bfloat162float(cv.h);
}

// ---------------- K0: mask element-width autodetect ----------------
__global__ __launch_bounds__(64) void detect_kernel(
    const unsigned char* __restrict__ a, int* __restrict__ flag) {
  int t = threadIdx.x;
  int v = a[t * 4 + 1] | a[t * 4 + 2] | a[t * 4 + 3];
#pragma unroll
  for (int o = 1; o < 64; o <<= 1) v |= __shfl_xor(v, o);
  if (t == 0) *flag = (v == 0) ? 4 : 1;
}

// ------------- K0b: bit-pack masks, word-per-thread, coalesced -------------
__global__ __launch_bounds__(128) void compress_kernel(
    const unsigned char* __restrict__ am, const unsigned char* __restrict__ lm,
    const int* __restrict__ mflag, unsigned int* __restrict__ abits,
    unsigned int* __restrict__ lbits) {
  const int row = blockIdx.x;
  const int t = threadIdx.x;  // word index within row (0..127)
  const int ms = *mflag;
  unsigned int wa = 0, wl = 0;
  const size_t gi = (size_t)row * (S / 4) + t * 8;  // in 4-elem granules
  if (ms == 1) {
    const uchar4* pa = reinterpret_cast<const uchar4*>(am) + gi;
    const uchar4* pl = reinterpret_cast<const uchar4*>(lm) + gi;
#pragma unroll
    for (int j = 0; j < 8; j++) {
      uchar4 va = pa[j], vl = pl[j];
      wa |= (unsigned)(va.x != 0) << (j * 4) | (unsigned)(va.y != 0) << (j * 4 + 1) |
            (unsigned)(va.z != 0) << (j * 4 + 2) | (unsigned)(va.w != 0) << (j * 4 + 3);
      wl |= (unsigned)(vl.x != 0) << (j * 4) | (unsigned)(vl.y != 0) << (j * 4 + 1) |
            (unsigned)(vl.z != 0) << (j * 4 + 2) | (unsigned)(vl.w != 0) << (j * 4 + 3);
    }
  } else {
    const int4* pa = reinterpret_cast<const int4*>(am) + gi;
    const int4* pl = reinterpret_cast<const int4*>(lm) + gi;
#pragma unroll
    for (int j = 0; j < 8; j++) {
      int4 va = pa[j], vl = pl[j];
      wa |= (unsigned)(va.x != 0) << (j * 4) | (unsigned)(va.y != 0) << (j * 4 + 1) |
            (unsigned)(va.z != 0) << (j * 4 + 2) | (unsigned)(va.w != 0) << (j * 4 + 3);
      wl |= (unsigned)(vl.x != 0) << (j * 4) | (unsigned)(vl.y != 0) << (j * 4 + 1) |
            (unsigned)(vl.z != 0) << (j * 4 + 2) | (unsigned)(vl.w != 0) << (j * 4 + 3);
    }
  }
  abits[row * SW + t] = wa;
  lbits[row * SW + t] = wl;
}

// ---------------- K1: LayerNorm + bf16 hi/lo split ----------------
__global__ __launch_bounds__(256) void ln_kernel(
    const float* __restrict__ x, const float* __restrict__ g,
    const float* __restrict__ b, unsigned short* __restrict__ xnh,
    unsigned short* __restrict__ xnl) {
  int row = blockIdx.x;
  int t = threadIdx.x;
  float2 v = reinterpret_cast<const float2*>(x + (size_t)row * D)[t];
  float s = v.x + v.y;
  float s2 = v.x * v.x + v.y * v.y;
#pragma unroll
  for (int o = 1; o < 64; o <<= 1) {
    s += __shfl_xor(s, o);
    s2 += __shfl_xor(s2, o);
  }
  __shared__ float red[8];
  int wid = t >> 6;
  if ((t & 63) == 0) { red[wid] = s; red[4 + wid] = s2; }
  __syncthreads();
  s = red[0] + red[1] + red[2] + red[3];
  s2 = red[4] + red[5] + red[6] + red[7];
  float mu = s * (1.f / D);
  float var = s2 * (1.f / D) - mu * mu;
  float rsig = rsqrtf(var + 1e-5f);
  int i0 = 2 * t, i1 = 2 * t + 1;
  float xn0 = (v.x - mu) * rsig * g[i0] + b[i0];
  float xn1 = (v.y - mu) * rsig * g[i1] + b[i1];
  unsigned short h0 = f2bf(xn0), h1 = f2bf(xn1);
  size_t base = (size_t)row * D;
  xnh[base + i0] = h0;
  xnh[base + i1] = h1;
  xnl[base + i0] = f2bf(xn0 - bf2f(h0));
  xnl[base + i1] = f2bf(xn1 - bf2f(h1));
}

// ------------- K2: weight convert + LDS-tiled transpose -------------
__global__ __launch_bounds__(256) void wsplit_kernel(
    const float* __restrict__ Wq, const float* __restrict__ Wk,
    const float* __restrict__ Wv, const float* __restrict__ Wo,
    unsigned short* __restrict__ qh, unsigned short* __restrict__ ql,
    unsigned short* __restrict__ kh, unsigned short* __restrict__ kl,
    unsigned short* __restrict__ vh, unsigned short* __restrict__ oh) {
  __shared__ float tile[64][65];
  int m = blockIdx.z;
  const float* W = (m == 0) ? Wq : (m == 1) ? Wk : (m == 2) ? Wv : Wo;
  int bx = blockIdx.x * 64;
  int by = blockIdx.y * 64;
  int tx = threadIdx.x & 63, ty = threadIdx.x >> 6;
#pragma unroll
  for (int i = 0; i < 16; i++) {
    int r = ty + i * 4;
    tile[r][tx] = W[(size_t)(by + r) * D + bx + tx];
  }
  __syncthreads();
#pragma unroll
  for (int i = 0; i < 16; i++) {
    int r = ty + i * 4;
    float w = tile[tx][r];
    unsigned short hi = f2bf(w);
    size_t to = (size_t)(bx + r) * D + by + tx;
    if (m == 0) { qh[to] = hi; ql[to] = f2bf(w - bf2f(hi)); }
    else if (m == 1) { kh[to] = hi; kl[to] = f2bf(w - bf2f(hi)); }
    else if (m == 2) { vh[to] = hi; }
    else { oh[to] = hi; }
  }
}

// ---------------- K3: QKV projections (MFMA) ----------------
__global__ __launch_bounds__(256) void qkv_kernel(
    const unsigned short* __restrict__ xnh, const unsigned short* __restrict__ xnl,
    const unsigned short* __restrict__ wqh, const unsigned short* __restrict__ wql,
    const unsigned short* __restrict__ wkh, const unsigned short* __restrict__ wkl,
    const unsigned short* __restrict__ wvh,
    const float* __restrict__ bq, const float* __restrict__ bk,
    const float* __restrict__ bv,
    unsigned short* __restrict__ Qb, unsigned short* __restrict__ Kb,
    unsigned short* __restrict__ VT) {
  int z = blockIdx.z;
  int wave = threadIdx.x >> 6, lane = threadIdx.x & 63;
  int lg = lane >> 4, lr = lane & 15;
  int rtile = blockIdx.x * 64 + wave * 16;
  int ctile = blockIdx.y * 64;
  const unsigned short* wh = (z == 0) ? wqh : (z == 1) ? wkh : wvh;
  const unsigned short* wl = (z == 0) ? wql : wkl;
  const float* bias = (z == 0) ? bq : (z == 1) ? bk : bv;
  f32x4 zero = {0.f, 0.f, 0.f, 0.f};
  f32x4 acc[4] = {zero, zero, zero, zero};
  int ar = rtile + lr;
  const unsigned short* ap = xnh + (size_t)ar * D + lg * 8;
  const unsigned short* apl = xnl + (size_t)ar * D + lg * 8;
  for (int kk = 0; kk < D; kk += 32) {
    bf16x8 ah = *(const bf16x8*)(ap + kk);
    bf16x8 al = {};
    if (z < 2) al = *(const bf16x8*)(apl + kk);
#pragma unroll
    for (int nt = 0; nt < 4; nt++) {
      size_t bo_ = (size_t)(ctile + nt * 16 + lr) * D + kk + lg * 8;
      bf16x8 bh = *(const bf16x8*)(wh + bo_);
      acc[nt] = mfma16(ah, bh, acc[nt]);
      if (z < 2) {
        bf16x8 bl = *(const bf16x8*)(wl + bo_);
        acc[nt] = mfma16(ah, bl, acc[nt]);
        acc[nt] = mfma16(al, bh, acc[nt]);
      }
    }
  }
#pragma unroll
  for (int nt = 0; nt < 4; nt++) {
    int col = ctile + nt * 16 + lr;
    float bb = bias[col];
#pragma unroll
    for (int r = 0; r < 4; r++) {
      int row = rtile + lg * 4 + r;
      float val = acc[nt][r] + bb;
      if (z == 0) Qb[(size_t)row * D + col] = f2bf(val);
      else if (z == 1) Kb[(size_t)row * D + col] = f2bf(val);
      else VT[(size_t)col * S + row] = f2bf(val);
    }
  }
}

// ---------------- K4a: attention row-sum pass (key-parallel) ----------------
// Block = 16q x 8 heads x 1024-key chunk; 8 waves, wave = head. Grid 256x4 =
// 1024 blocks -> 4 blocks/CU = 100% occupancy. Deterministic per-chunk
// partial sums (no atomics). Same fma/exp2 chain as write pass -> identical
// scores -> exact normalization.
__global__ __launch_bounds__(512, 8) void attn_sum_kernel(
    const unsigned short* __restrict__ Qb, const unsigned short* __restrict__ Kb,
    const unsigned int* __restrict__ abits, const unsigned int* __restrict__ lbits,
    const float* __restrict__ coords, float* __restrict__ Lpart) {
  __shared__ float dm[16][132];
  const int tid = threadIdx.x;
  const int wave = tid >> 6, lane = tid & 63;
  const int h = wave;
  const int lg = lane >> 4, lr = lane & 15;
  const int qbase = blockIdx.x * 16;
  const int kc = blockIdx.y;
  const float L2E = 1.4426950408889634f;
  const float A2 = 0.125f * L2E;
  const float B2 = exp2f(-(float)(h + 1)) * L2E;
  const float C2 = -50.f * L2E;
  bf16x8 qf0, qf1;
  {
    const unsigned short* qp = Qb + (size_t)(qbase + lr) * D + h * HD + lg * 8;
    qf0 = *(const bf16x8*)qp;
    qf1 = *(const bf16x8*)(qp + 32);
  }
  float lsum[4] = {0.f, 0.f, 0.f, 0.f};
  const int kt0 = kc * (S / KC_SUM);
  for (int kt = kt0; kt < kt0 + S / KC_SUM; kt += 128) {
    __syncthreads();
#pragma unroll
    for (int p = 0; p < 4; p++) {
      int idx = tid + p * 512;
      int qi = idx >> 7, kj = idx & 127;
      int q = qbase + qi, k = kt + kj;
      int wi = q * SW + (k >> 5);
      float dv = 0.f;
      if ((abits[wi] >> (kj & 31)) & 1u) dv = 1e30f;
      else if ((lbits[wi] >> (kj & 31)) & 1u) {
        float dx = coords[2 * q] - coords[2 * k];
        float dy = coords[2 * q + 1] - coords[2 * k + 1];
        dv = sqrtf(dx * dx + dy * dy + 1e-12f);
      }
      dm[qi][kj] = dv;
    }
    __syncthreads();
#pragma unroll
    for (int kk = 0; kk < 8; kk++) {
      const unsigned short* kp = Kb + (size_t)(kt + kk * 16 + lr) * D + h * HD + lg * 8;
      bf16x8 kf0 = *(const bf16x8*)kp;
      bf16x8 kf1 = *(const bf16x8*)(kp + 32);
      f32x4 c = {0.f, 0.f, 0.f, 0.f};
      c = mfma16(qf0, kf0, c);
      c = mfma16(qf1, kf1, c);
#pragma unroll
      for (int r = 0; r < 4; r++) {
        float t = fmaf(c[r], A2, fmaf(-B2, dm[lg * 4 + r][kk * 16 + lr], C2));
        lsum[r] += exp2f(t);
      }
    }
  }
#pragma unroll
  for (int r = 0; r < 4; r++) {
#pragma unroll
    for (int o = 1; o < 16; o <<= 1) lsum[r] += __shfl_xor(lsum[r], o);
  }
  if (lr == 0) {
#pragma unroll
    for (int r = 0; r < 4; r++) {
      Lpart[((size_t)kc * H + h) * S + qbase + lg * 4 + r] = lsum[r];
    }
  }
}

// ---------------- K4b: attention write + PV pass (key-parallel) -------------
// Block = 16q x 8 heads x 2048-key chunk; grid 256x2 = 512 blocks -> 2-3/CU.
// PV partials to fp32 OHp[KC_WR][S][D]; oproj sums them.
__global__ __launch_bounds__(512, 4) void attn_write_kernel(
    const unsigned short* __restrict__ Qb, const unsigned short* __restrict__ Kb,
    const unsigned short* __restrict__ VT,
    const unsigned int* __restrict__ abits, const unsigned int* __restrict__ lbits,
    const float* __restrict__ coords, const float* __restrict__ Lpart,
    float* __restrict__ attn, float* __restrict__ OHp) {
  __shared__ float dm[16][132];
  __shared__ __align__(16) unsigned short pB[8][16][136];
  const int tid = threadIdx.x;
  const int wave = tid >> 6, lane = tid & 63;
  const int h = wave;
  const int lg = lane >> 4, lr = lane & 15;
  const int qbase = blockIdx.x * 16;
  const int kc = blockIdx.y;
  const float L2E = 1.4426950408889634f;
  const float A2 = 0.125f * L2E;
  const float B2 = exp2f(-(float)(h + 1)) * L2E;
  const float C2 = -50.f * L2E;
  bf16x8 qf0, qf1;
  {
    const unsigned short* qp = Qb + (size_t)(qbase + lr) * D + h * HD + lg * 8;
    qf0 = *(const bf16x8*)qp;
    qf1 = *(const bf16x8*)(qp + 32);
  }
  float rl[4];
#pragma unroll
  for (int r = 0; r < 4; r++) {
    int row = qbase + lg * 4 + r;
    float ls = 0.f;
#pragma unroll
    for (int c = 0; c < KC_SUM; c++) ls += Lpart[((size_t)c * H + h) * S + row];
    rl[r] = 1.f / ls;
  }
  f32x4 zero = {0.f, 0.f, 0.f, 0.f};
  f32x4 oacc[4] = {zero, zero, zero, zero};
  const int kt0 = kc * (S / KC_WR);
  for (int kt = kt0; kt < kt0 + S / KC_WR; kt += 128) {
    __syncthreads();
#pragma unroll
    for (int p = 0; p < 4; p++) {
      int idx = tid + p * 512;
      int qi = idx >> 7, kj = idx & 127;
      int q = qbase + qi, k = kt + kj;
      int wi = q * SW + (k >> 5);
      float dv = 0.f;
      if ((abits[wi] >> (kj & 31)) & 1u) dv = 1e30f;
      else if ((lbits[wi] >> (kj & 31)) & 1u) {
        float dx = coords[2 * q] - coords[2 * k];
        float dy = coords[2 * q + 1] - coords[2 * k + 1];
        dv = sqrtf(dx * dx + dy * dy + 1e-12f);
      }
      dm[qi][kj] = dv;
    }
    __syncthreads();
#pragma unroll
    for (int kk = 0; kk < 8; kk++) {
      const unsigned short* kp = Kb + (size_t)(kt + kk * 16 + lr) * D + h * HD + lg * 8;
      bf16x8 kf0 = *(const bf16x8*)kp;
      bf16x8 kf1 = *(const bf16x8*)(kp + 32);
      f32x4 c = {0.f, 0.f, 0.f, 0.f};
      c = mfma16(qf0, kf0, c);
      c = mfma16(qf1, kf1, c);
#pragma unroll
      for (int r = 0; r < 4; r++) {
        float t = fmaf(c[r], A2, fmaf(-B2, dm[lg * 4 + r][kk * 16 + lr], C2));
        float pv = exp2f(t) * rl[r];
        __builtin_nontemporal_store(
            pv, &attn[((size_t)h * S + qbase + lg * 4 + r) * S + kt + kk * 16 + lr]);
        pB[wave][lg * 4 + r][kk * 16 + lr] = f2bf(pv);
      }
    }
    // pB produced+consumed by the same wave (compiler lgkmcnt orders it).
#pragma unroll
    for (int ks = 0; ks < 4; ks++) {
      bf16x8 pa = *(const bf16x8*)&pB[wave][lr][ks * 32 + lg * 8];
#pragma unroll
      for (int nt = 0; nt < 4; nt++) {
        const unsigned short* vp =
            VT + (size_t)(h * HD + nt * 16 + lr) * S + kt + ks * 32 + lg * 8;
        bf16x8 vb = *(const bf16x8*)vp;
        oacc[nt] = mfma16(pa, vb, oacc[nt]);
      }
    }
  }
#pragma unroll
  for (int nt = 0; nt < 4; nt++) {
#pragma unroll
    for (int r = 0; r < 4; r++) {
      OHp[((size_t)kc * S + qbase + lg * 4 + r) * D + h * HD + nt * 16 + lr] =
          oacc[nt][r];
    }
  }
}

// ---------------- K5: output projection (sums the PV partials) ----------------
__global__ __launch_bounds__(256) void oproj_kernel(
    const float* __restrict__ OHp, const unsigned short* __restrict__ woh,
    const float* __restrict__ bo, float* __restrict__ out) {
  int wave = threadIdx.x >> 6, lane = threadIdx.x & 63;
  int lg = lane >> 4, lr = lane & 15;
  int rtile = blockIdx.x * 64 + wave * 16;
  int ctile = blockIdx.y * 64;
  f32x4 zero = {0.f, 0.f, 0.f, 0.f};
  f32x4 acc[4] = {zero, zero, zero, zero};
  const float* p0 = OHp + (size_t)(rtile + lr) * D;
  const float* p1 = OHp + ((size_t)S + rtile + lr) * D;
  for (int kk = 0; kk < D; kk += 32) {
    int base = kk + lg * 8;
    float4 a0 = *(const float4*)(p0 + base);
    float4 a1 = *(const float4*)(p0 + base + 4);
    float4 b0 = *(const float4*)(p1 + base);
    float4 b1 = *(const float4*)(p1 + base + 4);
    union { unsigned short u[8]; bf16x8 v; } A;
    A.u[0] = f2bf(a0.x + b0.x); A.u[1] = f2bf(a0.y + b0.y);
    A.u[2] = f2bf(a0.z + b0.z); A.u[3] = f2bf(a0.w + b0.w);
    A.u[4] = f2bf(a1.x + b1.x); A.u[5] = f2bf(a1.y + b1.y);
    A.u[6] = f2bf(a1.z + b1.z); A.u[7] = f2bf(a1.w + b1.w);
#pragma unroll
    for (int nt = 0; nt < 4; nt++) {
      bf16x8 b = *(const bf16x8*)(woh + (size_t)(ctile + nt * 16 + lr) * D + kk + lg * 8);
      acc[nt] = mfma16(A.v, b, acc[nt]);
    }
  }
#pragma unroll
  for (int nt = 0; nt < 4; nt++) {
    int col = ctile + nt * 16 + lr;
    float bb = bo[col];
#pragma unroll
    for (int r = 0; r < 4; r++) {
      out[(size_t)(rtile + lg * 4 + r) * D + col] = acc[nt][r] + bb;
    }
  }
}

extern "C" void kernel_launch(void* const* d_in, const int* in_sizes, int n_in,
                              void* d_out, int out_size, void* d_ws,
                              size_t ws_size, hipStream_t stream) {
  const float* x = (const float*)d_in[0];
  const float* coords = (const float*)d_in[1];
  const unsigned char* amask = (const unsigned char*)d_in[2];
  const unsigned char* almask = (const unsigned char*)d_in[3];
  const float* ln_g = (const float*)d_in[4];
  const float* ln_b = (const float*)d_in[5];
  const float* Wq = (const float*)d_in[6];
  const float* bq = (const float*)d_in[7];
  const float* Wk = (const float*)d_in[8];
  const float* bk = (const float*)d_in[9];
  const float* Wv = (const float*)d_in[10];
  const float* bv = (const float*)d_in[11];
  const float* Wo = (const float*)d_in[12];
  const float* bo = (const float*)d_in[13];

  float* out = (float*)d_out;
  float* attn = out + (size_t)S * D;  // outputs concatenated: out, then attn

  char* w = (char*)d_ws;
  int* mflag = (int*)w; w += 256;
  const size_t sz_xn = (size_t)S * D * 2;     // 4 MB
  const size_t sz_w = (size_t)D * D * 2;      // 0.5 MB
  const size_t sz_bits = (size_t)S * SW * 4;  // 2 MB
  unsigned short* xnh = (unsigned short*)w; w += sz_xn;
  unsigned short* xnl = (unsigned short*)w; w += sz_xn;
  unsigned short* wqh = (unsigned short*)w; w += sz_w;
  unsigned short* wql = (unsigned short*)w; w += sz_w;
  unsigned short* wkh = (unsigned short*)w; w += sz_w;
  unsigned short* wkl = (unsigned short*)w; w += sz_w;
  unsigned short* wvh = (unsigned short*)w; w += sz_w;
  unsigned short* woh = (unsigned short*)w; w += sz_w;
  unsigned short* Qb = (unsigned short*)w; w += sz_xn;
  unsigned short* Kb = (unsigned short*)w; w += sz_xn;
  unsigned short* VT = (unsigned short*)w; w += sz_xn;
  unsigned int* abits = (unsigned int*)w; w += sz_bits;
  unsigned int* lbits = (unsigned int*)w; w += sz_bits;
  float* Lpart = (float*)w; w += (size_t)KC_SUM * H * S * 4;      // 0.5 MB
  float* OHp = (float*)w; w += (size_t)KC_WR * S * D * 4;         // 16 MB

  detect_kernel<<<1, 64, 0, stream>>>(amask, mflag);
  compress_kernel<<<S, 128, 0, stream>>>(amask, almask, mflag, abits, lbits);
  ln_kernel<<<S, 256, 0, stream>>>(x, ln_g, ln_b, xnh, xnl);
  wsplit_kernel<<<dim3(8, 8, 4), 256, 0, stream>>>(Wq, Wk, Wv, Wo, wqh, wql,
                                                   wkh, wkl, wvh, woh);
  qkv_kernel<<<dim3(64, 8, 3), 256, 0, stream>>>(xnh, xnl, wqh, wql, wkh, wkl,
                                                 wvh, bq, bk, bv, Qb, Kb, VT);
  attn_sum_kernel<<<dim3(S / 16, KC_SUM), 512, 0, stream>>>(
      Qb, Kb, abits, lbits, coords, Lpart);
  attn_write_kernel<<<dim3(S / 16, KC_WR), 512, 0, stream>>>(
      Qb, Kb, VT, abits, lbits, coords, Lpart, attn, OHp);
  oproj_kernel<<<dim3(64, 8), 256, 0, stream>>>(OHp, woh, bo, out);
}